// Round 4
// baseline (11177.645 us; speedup 1.0000x reference)
//
// R4: NO cooperative launch (R2/R3 coop launches failed silently -> poison out).
// Grid sync between LSTM steps = kernel boundary: 512 per-step launches.
// Step kernel: 256 blocks x 256 thr; block=(dir, 32-row half, 8 h-cols x 4 gates);
// h(s-1) fp16 LDS tile (XOR chunk swizzle), U streamed from L2, fp32 math.
// Bulk storage xz/hs0/h fp16; c-state fp32. GEMMs/embed/head as R3.
#include <hip/hip_runtime.h>
#include <hip/hip_fp16.h>
#include <math.h>

#define NB   64
#define NS   256
#define ND   300
#define NH   512
#define N4H  2048

__global__ void embed_kernel(const int* __restrict__ text,
                             const float* __restrict__ emb,
                             float* __restrict__ x) {
  int idx = blockIdx.x * 256 + threadIdx.x;
  const int total = NB * NS * ND;
  for (; idx < total; idx += gridDim.x * 256) {
    int bs = idx / ND;
    int d  = idx - bs * ND;
    x[idx] = emb[text[bs] * ND + d];
  }
}

__device__ inline float loadA(const float* A, size_t i) { return A[i]; }
__device__ inline float loadA(const __half* A, size_t i) { return __half2float(A[i]); }

__device__ inline void storeC(float* C, size_t i, const float4& o0, const float4& o1) {
  *(float4*)(C + i) = o0;
  *(float4*)(C + i + 4) = o1;
}
__device__ inline void storeC(__half* C, size_t i, const float4& o0, const float4& o1) {
  __align__(16) __half tmp[8];
  tmp[0] = __float2half(o0.x); tmp[1] = __float2half(o0.y);
  tmp[2] = __float2half(o0.z); tmp[3] = __float2half(o0.w);
  tmp[4] = __float2half(o1.x); tmp[5] = __float2half(o1.y);
  tmp[6] = __float2half(o1.z); tmp[7] = __float2half(o1.w);
  *(uint4*)(C + i) = *(const uint4*)tmp;
}

// C[M,N] = A[M,K] @ W[K,N] + bias ; ACT: 0 none, 1 leaky(0.2)
template <typename AT, typename CT, int ACT>
__global__ __launch_bounds__(256) void gemm_kernel(
    const AT* __restrict__ A, const float* __restrict__ W,
    const float* __restrict__ bias, CT* __restrict__ C,
    int M, int N, int K) {
  __shared__ __align__(16) float As[8][128];
  __shared__ __align__(16) float Bs[8][128];
  const int t  = threadIdx.x;
  const int bn = blockIdx.x * 128;
  const int bm = blockIdx.y * 128;
  const int tx = t & 15, ty = t >> 4;
  const int lm  = t >> 1;
  const int lk4 = (t & 1) * 4;
  const int lbk = t >> 5;
  const int lbn = (t & 31) * 4;
  float acc[8][8];
#pragma unroll
  for (int i = 0; i < 8; i++)
#pragma unroll
    for (int j = 0; j < 8; j++) acc[i][j] = 0.f;

  for (int k0 = 0; k0 < K; k0 += 8) {
#pragma unroll
    for (int i = 0; i < 4; i++) {
      int k = k0 + lk4 + i;
      int m = bm + lm;
      float v = 0.f;
      if (k < K && m < M) v = loadA(A, (size_t)m * K + k);
      As[lk4 + i][lm] = v;
    }
    {
      int k = k0 + lbk;
      float4 v = make_float4(0.f, 0.f, 0.f, 0.f);
      if (k < K) v = *(const float4*)(W + (size_t)k * N + bn + lbn);
      *(float4*)(&Bs[lbk][lbn]) = v;
    }
    __syncthreads();
#pragma unroll
    for (int kk = 0; kk < 8; kk++) {
      float a[8], b[8];
      *(float4*)(a)     = *(const float4*)(&As[kk][ty * 8]);
      *(float4*)(a + 4) = *(const float4*)(&As[kk][ty * 8 + 4]);
      *(float4*)(b)     = *(const float4*)(&Bs[kk][tx * 8]);
      *(float4*)(b + 4) = *(const float4*)(&Bs[kk][tx * 8 + 4]);
#pragma unroll
      for (int i = 0; i < 8; i++)
#pragma unroll
        for (int j = 0; j < 8; j++) acc[i][j] += a[i] * b[j];
    }
    __syncthreads();
  }
  float4 bv0 = *(const float4*)(bias + bn + tx * 8);
  float4 bv1 = *(const float4*)(bias + bn + tx * 8 + 4);
#pragma unroll
  for (int i = 0; i < 8; i++) {
    int m = bm + ty * 8 + i;
    if (m >= M) continue;
    float4 o0, o1;
    o0.x = acc[i][0] + bv0.x; o0.y = acc[i][1] + bv0.y;
    o0.z = acc[i][2] + bv0.z; o0.w = acc[i][3] + bv0.w;
    o1.x = acc[i][4] + bv1.x; o1.y = acc[i][5] + bv1.y;
    o1.z = acc[i][6] + bv1.z; o1.w = acc[i][7] + bv1.w;
    if (ACT == 1) {
      o0.x = o0.x >= 0.f ? o0.x : 0.2f * o0.x;  o0.y = o0.y >= 0.f ? o0.y : 0.2f * o0.y;
      o0.z = o0.z >= 0.f ? o0.z : 0.2f * o0.z;  o0.w = o0.w >= 0.f ? o0.w : 0.2f * o0.w;
      o1.x = o1.x >= 0.f ? o1.x : 0.2f * o1.x;  o1.y = o1.y >= 0.f ? o1.y : 0.2f * o1.y;
      o1.z = o1.z >= 0.f ? o1.z : 0.2f * o1.z;  o1.w = o1.w >= 0.f ? o1.w : 0.2f * o1.w;
    }
    storeC(C, (size_t)m * N + bn + tx * 8, o0, o1);
  }
}

// One LSTM time step, both directions. Grid 256 x 256.
// Block: dir = bi>>7, row-half rh = (bi>>6)&1 (32 rows), cb = bi&63 (8 h-cols).
// Thread: cg=t&7 -> (gate q=cg&3, col-pair jp=cg>>2), ks=(t>>3)&7 (64 k), wave rw=t>>6 (8 rows).
// h buffers (fp16) are (64 x 1024): fwd cols [0,512), bwd [512,1024). cbuf fp32 same shape.
__global__ __launch_bounds__(256) void lstm_step_kernel(
    const __half* __restrict__ xzf, const __half* __restrict__ xzb,
    const float* __restrict__ Uf, const float* __restrict__ Ub,
    const int* __restrict__ text,
    const __half* __restrict__ hprev, __half* __restrict__ hnext,
    float* __restrict__ cbuf, int s,
    __half* __restrict__ hs_out, float* __restrict__ hT_out) {
  __shared__ __align__(16) float s_zp[32 * 288];   // 36864 B; low 32KB doubles as fp16 h tile
  __shared__ __align__(16) float s_z[32 * 32];
  __half* s_h = (__half*)s_zp;

  const int t   = threadIdx.x;
  const int bi  = blockIdx.x;
  const int dir = bi >> 7;
  const int rh  = (bi >> 6) & 1;
  const int cb  = bi & 63;
  const int b0  = rh * 32;
  const int hc0 = cb * 8;
  const int tt  = dir ? (NS - 1 - s) : s;
  const __half* xz = dir ? xzb : xzf;
  const float* U = dir ? Ub : Uf;
  const int hbase = dir * NH;

  const int cg = t & 7;
  const int q  = cg & 3;
  const int jp = cg >> 2;
  const int ks = (t >> 3) & 7;
  const int rw = t >> 6;

  if (s > 0) {
    // stage h(s-1): 32 rows x 512 fp16, 16B-chunk XOR swizzle
#pragma unroll
    for (int i = 0; i < 8; i++) {
      int e   = i * 256 + t;
      int row = e >> 6;
      int ch  = e & 63;
      int pc  = ch ^ ((ch >> 3) & 7);
      *(uint4*)(s_h + row * 512 + pc * 8) =
          *(const uint4*)(hprev + (size_t)(b0 + row) * 1024 + hbase + ch * 8);
    }
    __syncthreads();
    float4 pacc[8];
#pragma unroll
    for (int r = 0; r < 8; r++) pacc[r] = make_float4(0.f, 0.f, 0.f, 0.f);
    const int ucol = q * NH + hc0 + jp * 4;
    int hoff[8];
#pragma unroll
    for (int kt = 0; kt < 8; kt++) hoff[kt] = (ks * 8 + (kt ^ ks)) * 8;
#pragma unroll
    for (int kt = 0; kt < 8; kt++) {
      float4 u[8];
#pragma unroll
      for (int kk = 0; kk < 8; kk++)
        u[kk] = *(const float4*)(U + (size_t)(ks * 64 + kt * 8 + kk) * N4H + ucol);
#pragma unroll
      for (int r = 0; r < 8; r++) {
        uint4 hraw = *(const uint4*)(s_h + (rw * 8 + r) * 512 + hoff[kt]);
        const __half2* hp2 = (const __half2*)&hraw;
        float hv[8];
#pragma unroll
        for (int p = 0; p < 4; p++) {
          float2 f = __half22float2(hp2[p]);
          hv[2 * p] = f.x; hv[2 * p + 1] = f.y;
        }
#pragma unroll
        for (int kk = 0; kk < 8; kk++) {
          pacc[r].x += hv[kk] * u[kk].x;
          pacc[r].y += hv[kk] * u[kk].y;
          pacc[r].z += hv[kk] * u[kk].z;
          pacc[r].w += hv[kk] * u[kk].w;
        }
      }
    }
    __syncthreads();   // all h-tile reads done; zpart overlays
    // zpart[r][zc][9], zc = q*8 + jp*4 + c
#pragma unroll
    for (int r = 0; r < 8; r++) {
      float* zp = &s_zp[(rw * 8 + r) * 288 + (q * 8 + jp * 4) * 9 + ks];
      zp[0] = pacc[r].x; zp[9] = pacc[r].y; zp[18] = pacc[r].z; zp[27] = pacc[r].w;
    }
  }
  __syncthreads();

  // reduce 8 k-partials per z, add xz
#pragma unroll
  for (int dd = 0; dd < 4; dd++) {
    int v = dd * 256 + t;
    int r = v >> 5, zc = v & 31;
    float sum = 0.f;
    if (s > 0) {
      const float* zp = &s_zp[r * 288 + zc * 9];
#pragma unroll
      for (int k = 0; k < 8; k++) sum += zp[k];
    }
    int gcol = (zc >> 3) * NH + hc0 + (zc & 7);
    sum += __half2float(xz[((size_t)(b0 + r) * NS + tt) * N4H + gcol]);
    s_z[r * 32 + zc] = sum;
  }
  __syncthreads();

  // gate update: one owner thread per (row r, h-col j)
  {
    int r = t >> 3, j = t & 7;
    float zi = s_z[r * 32 + j];
    float zf = s_z[r * 32 + 8 + j];
    float zg = s_z[r * 32 + 16 + j];
    float zo = s_z[r * 32 + 24 + j];
    size_t cidx = (size_t)(b0 + r) * 1024 + hbase + hc0 + j;
    float cprev = (s > 0) ? cbuf[cidx] : 0.f;
    float hold  = (s > 0) ? __half2float(hprev[cidx]) : 0.f;
    float ig = 1.f / (1.f + expf(-zi));
    float fg = 1.f / (1.f + expf(-zf));
    float gv = tanhf(zg);
    float og = 1.f / (1.f + expf(-zo));
    float cn = fg * cprev + ig * gv;
    float hn = og * tanhf(cn);
    bool m = text[(b0 + r) * NS + tt] != 0;
    float c = m ? cn : cprev;
    float h = m ? hn : hold;
    cbuf[cidx] = c;
    hnext[cidx] = __float2half(h);
    if (hs_out) hs_out[((size_t)(b0 + r) * NS + tt) * 1024 + hbase + hc0 + j] = __float2half(h);
    if (hT_out && s == NS - 1) hT_out[cidx] = h;
  }
}

__global__ void final_kernel(const float* __restrict__ a1, const float* __restrict__ w,
                             const float* __restrict__ bias, float* __restrict__ out) {
  const int b = blockIdx.x, t = threadIdx.x;
  float v = a1[b * 256 + t] * w[t];
#pragma unroll
  for (int off = 32; off > 0; off >>= 1) v += __shfl_down(v, off, 64);
  __shared__ float red[4];
  if ((t & 63) == 0) red[t >> 6] = v;
  __syncthreads();
  if (t == 0) out[b] = (red[0] + red[1]) + (red[2] + red[3]) + bias[0];
}

extern "C" void kernel_launch(void* const* d_in, const int* in_sizes, int n_in,
                              void* d_out, int out_size, void* d_ws, size_t ws_size,
                              hipStream_t stream) {
  const int*   text = (const int*)  d_in[0];
  const float* emb  = (const float*)d_in[1];
  const float* W0f  = (const float*)d_in[2];
  const float* U0f  = (const float*)d_in[3];
  const float* b0f  = (const float*)d_in[4];
  const float* W0b  = (const float*)d_in[5];
  const float* U0b  = (const float*)d_in[6];
  const float* b0b  = (const float*)d_in[7];
  const float* W1f  = (const float*)d_in[8];
  const float* U1f  = (const float*)d_in[9];
  const float* b1f  = (const float*)d_in[10];
  const float* W1b  = (const float*)d_in[11];
  const float* U1b  = (const float*)d_in[12];
  const float* b1b  = (const float*)d_in[13];
  const float* d0w  = (const float*)d_in[14];
  const float* d0b  = (const float*)d_in[15];
  const float* d1w  = (const float*)d_in[16];
  const float* d1b  = (const float*)d_in[17];
  const float* d2w  = (const float*)d_in[18];
  const float* d2b  = (const float*)d_in[19];
  float* out = (float*)d_out;

  // workspace carve: ~169 MB (R2/R3 ran at this footprint without faulting)
  char* p = (char*)d_ws;
  __half* xzA = (__half*)p;  p += (size_t)NB * NS * N4H * 2;   // 67 MB
  __half* xzB = (__half*)p;  p += (size_t)NB * NS * N4H * 2;   // 67 MB
  char* region1 = p;         p += (size_t)NB * NS * 1024 * 2;  // 33.5 MB
  float*  x_emb = (float*)region1;       // 19.7 MB fp32, dead before hs0 written
  __half* hs0   = (__half*)region1;      // 33.5 MB fp16
  __half* hp0  = (__half*)p;  p += 64 * 1024 * 2;
  __half* hp1  = (__half*)p;  p += 64 * 1024 * 2;
  float*  cbuf = (float*)p;   p += 64 * 1024 * 4;
  float*  feat = (float*)p;   p += 64 * 1024 * 4;
  float*  a0   = (float*)p;   p += 64 * 512 * 4;
  float*  a1   = (float*)p;   p += 64 * 256 * 4;

  hipLaunchKernelGGL(embed_kernel, dim3(4096), dim3(256), 0, stream, text, emb, x_emb);

  dim3 gx(16, 128);
  gemm_kernel<float, __half, 0><<<gx, dim3(256), 0, stream>>>(x_emb, W0f, b0f, xzA, 16384, 2048, 300);
  gemm_kernel<float, __half, 0><<<gx, dim3(256), 0, stream>>>(x_emb, W0b, b0b, xzB, 16384, 2048, 300);

  for (int s = 0; s < NS; s++) {
    const __half* hp = (s & 1) ? hp1 : hp0;
    __half*       hn = (s & 1) ? hp0 : hp1;
    lstm_step_kernel<<<dim3(256), dim3(256), 0, stream>>>(
        xzA, xzB, U0f, U0b, text, hp, hn, cbuf, s, hs0, (float*)nullptr);
  }

  gemm_kernel<__half, __half, 0><<<gx, dim3(256), 0, stream>>>(hs0, W1f, b1f, xzA, 16384, 2048, 1024);
  gemm_kernel<__half, __half, 0><<<gx, dim3(256), 0, stream>>>(hs0, W1b, b1b, xzB, 16384, 2048, 1024);

  for (int s = 0; s < NS; s++) {
    const __half* hp = (s & 1) ? hp1 : hp0;
    __half*       hn = (s & 1) ? hp0 : hp1;
    lstm_step_kernel<<<dim3(256), dim3(256), 0, stream>>>(
        xzA, xzB, U1f, U1b, text, hp, hn, cbuf, s, (__half*)nullptr, feat);
  }

  gemm_kernel<float, float, 1><<<dim3(4, 1), dim3(256), 0, stream>>>(feat, d0w, d0b, a0, 64, 512, 1024);
  gemm_kernel<float, float, 1><<<dim3(2, 1), dim3(256), 0, stream>>>(a0, d1w, d1b, a1, 64, 256, 512);
  hipLaunchKernelGGL(final_kernel, dim3(64), dim3(256), 0, stream, a1, d2w, d2b, out);
}

// Round 6
// 9304.947 us; speedup vs baseline: 1.2013x; 1.2013x over previous
//
// R6: fix R5's d_ws overflow (Wt buffers pushed footprint to 179.8MB > ws_size;
// adjacent-mapping corruption changed restored inputs -> post-timing divergence).
// Weight transpose now happens inside gemm_mfma via an LDS fp32 bounce tile;
// carve is byte-identical to R4's proven-safe 168,955,904 B.
// Pipeline: embed(fp16,pad320) -> mfma gemm xz0 f,b -> 256 step launches (L0)
// -> mfma gemm xz1 f,b -> 256 step launches (L1) -> fp32 head -> final dot.
#include <hip/hip_runtime.h>
#include <hip/hip_fp16.h>
#include <math.h>

#define NB   64
#define NS   256
#define ND   300
#define NDP  320       // ND padded to multiple of 32
#define NH   512
#define N4H  2048

typedef _Float16 half8_t __attribute__((ext_vector_type(8)));
typedef float    f32x4_t __attribute__((ext_vector_type(4)));

// ---------- embedding: gather + fp16 convert + zero-pad K to 320 ----------
__global__ void embed_f16_kernel(const int* __restrict__ text,
                                 const float* __restrict__ emb,
                                 _Float16* __restrict__ x) {
  int idx = blockIdx.x * 256 + threadIdx.x;
  const int total = NB * NS * NDP;
  for (; idx < total; idx += gridDim.x * 256) {
    int bs = idx / NDP;
    int d  = idx - bs * NDP;
    x[idx] = (d < ND) ? (_Float16)emb[(size_t)text[bs] * ND + d] : (_Float16)0.f;
  }
}

// ---------- MFMA GEMM: C[M,N] (fp16) = A[M,K] (fp16) @ W[Kw,N] (fp32) + bias ----
// W is K-major (row k = N floats). Transpose+convert happens per-tile in LDS.
// M%128==0, N%128==0, K%32==0, Kw<=K (rows >= Kw read as zero).
// Grid (N/128, M/128), 256 threads (4 waves). Wave w: rows [w*32, w*32+32).
__global__ __launch_bounds__(256) void gemm_mfma_kernel(
    const _Float16* __restrict__ A, const float* __restrict__ W,
    const float* __restrict__ bias, __half* __restrict__ C,
    int M, int N, int K, int Kw) {
  __shared__ __align__(16) _Float16 as[128][40];    // pad: bank stride 20 -> 2-way max
  __shared__ __align__(16) _Float16 ws16[128][40];
  __shared__ __align__(16) float    ws32[32][132];  // fp32 W tile, +4 pad
  const int t = threadIdx.x;
  const int w = t >> 6;
  const int l = t & 63;
  const int lane16 = l & 15;
  const int kq = l >> 4;          // quad 0..3
  const int bm = blockIdx.y * 128;
  const int bn = blockIdx.x * 128;
  const int lr  = t >> 2;         // A staging row 0..63 (x2)
  const int lsg = t & 3;          // 8-half segment within BK=32
  const int wk  = t >> 3;         // W staging k 0..31
  const int wns = t & 7;          // W staging 16-col segment
  const int rn  = t >> 1;         // repack n 0..127
  const int rk0 = (t & 1) * 2;    // repack kq base {0,2}

  f32x4_t acc[2][8];
#pragma unroll
  for (int i = 0; i < 2; i++)
#pragma unroll
    for (int j = 0; j < 8; j++) acc[i][j] = (f32x4_t){0.f, 0.f, 0.f, 0.f};

  for (int k0 = 0; k0 < K; k0 += 32) {
    // stage A (fp16, vectorized) and W rows (fp32, coalesced)
#pragma unroll
    for (int h = 0; h < 2; h++) {
      int m = h * 64 + lr;
      *(uint4*)&as[m][lsg * 8] = *(const uint4*)(A + (size_t)(bm + m) * K + k0 + lsg * 8);
    }
    if (k0 + wk < Kw) {
#pragma unroll
      for (int i = 0; i < 4; i++)
        *(float4*)&ws32[wk][wns * 16 + i * 4] =
            *(const float4*)(W + (size_t)(k0 + wk) * N + bn + wns * 16 + i * 4);
    } else {
#pragma unroll
      for (int i = 0; i < 4; i++)
        *(float4*)&ws32[wk][wns * 16 + i * 4] = make_float4(0.f, 0.f, 0.f, 0.f);
    }
    __syncthreads();
    // repack: ws16[n][k] = (fp16) ws32[k][n]
#pragma unroll
    for (int g = 0; g < 2; g++) {
      int kqq = rk0 + g;
      half8_t hv;
#pragma unroll
      for (int jj = 0; jj < 8; jj++) hv[jj] = (_Float16)ws32[kqq * 8 + jj][rn];
      *(half8_t*)&ws16[rn][kqq * 8] = hv;
    }
    __syncthreads();
    half8_t afrag[2];
#pragma unroll
    for (int i = 0; i < 2; i++)
      afrag[i] = *(const half8_t*)&as[w * 32 + i * 16 + lane16][kq * 8];
#pragma unroll
    for (int j = 0; j < 8; j++) {
      half8_t bfrag = *(const half8_t*)&ws16[j * 16 + lane16][kq * 8];
#pragma unroll
      for (int i = 0; i < 2; i++)
        acc[i][j] = __builtin_amdgcn_mfma_f32_16x16x32_f16(afrag[i], bfrag, acc[i][j], 0, 0, 0);
    }
    __syncthreads();
  }
  // epilogue: C/D layout col=lane&15, row=quad*4+reg
#pragma unroll
  for (int j = 0; j < 8; j++) {
    int col = bn + j * 16 + lane16;
    float bv = bias[col];
#pragma unroll
    for (int i = 0; i < 2; i++) {
      int rbase = bm + w * 32 + i * 16 + kq * 4;
#pragma unroll
      for (int r = 0; r < 4; r++)
        C[(size_t)(rbase + r) * N + col] = __float2half(acc[i][j][r] + bv);
    }
  }
}

// ---------- fp32 SMEM GEMM (head only) ----------
template <int ACT>
__global__ __launch_bounds__(256) void gemm_kernel(
    const float* __restrict__ A, const float* __restrict__ W,
    const float* __restrict__ bias, float* __restrict__ C,
    int M, int N, int K) {
  __shared__ __align__(16) float As[8][128];
  __shared__ __align__(16) float Bs[8][128];
  const int t  = threadIdx.x;
  const int bn = blockIdx.x * 128;
  const int bm = blockIdx.y * 128;
  const int tx = t & 15, ty = t >> 4;
  const int lm  = t >> 1;
  const int lk4 = (t & 1) * 4;
  const int lbk = t >> 5;
  const int lbn = (t & 31) * 4;
  float acc[8][8];
#pragma unroll
  for (int i = 0; i < 8; i++)
#pragma unroll
    for (int j = 0; j < 8; j++) acc[i][j] = 0.f;

  for (int k0 = 0; k0 < K; k0 += 8) {
#pragma unroll
    for (int i = 0; i < 4; i++) {
      int k = k0 + lk4 + i;
      int m = bm + lm;
      float v = 0.f;
      if (k < K && m < M) v = A[(size_t)m * K + k];
      As[lk4 + i][lm] = v;
    }
    {
      int k = k0 + lbk;
      float4 v = make_float4(0.f, 0.f, 0.f, 0.f);
      if (k < K) v = *(const float4*)(W + (size_t)k * N + bn + lbn);
      *(float4*)(&Bs[lbk][lbn]) = v;
    }
    __syncthreads();
#pragma unroll
    for (int kk = 0; kk < 8; kk++) {
      float a[8], b[8];
      *(float4*)(a)     = *(const float4*)(&As[kk][ty * 8]);
      *(float4*)(a + 4) = *(const float4*)(&As[kk][ty * 8 + 4]);
      *(float4*)(b)     = *(const float4*)(&Bs[kk][tx * 8]);
      *(float4*)(b + 4) = *(const float4*)(&Bs[kk][tx * 8 + 4]);
#pragma unroll
      for (int i = 0; i < 8; i++)
#pragma unroll
        for (int j = 0; j < 8; j++) acc[i][j] += a[i] * b[j];
    }
    __syncthreads();
  }
  float4 bv0 = *(const float4*)(bias + bn + tx * 8);
  float4 bv1 = *(const float4*)(bias + bn + tx * 8 + 4);
#pragma unroll
  for (int i = 0; i < 8; i++) {
    int m = bm + ty * 8 + i;
    if (m >= M) continue;
    float4 o0, o1;
    o0.x = acc[i][0] + bv0.x; o0.y = acc[i][1] + bv0.y;
    o0.z = acc[i][2] + bv0.z; o0.w = acc[i][3] + bv0.w;
    o1.x = acc[i][4] + bv1.x; o1.y = acc[i][5] + bv1.y;
    o1.z = acc[i][6] + bv1.z; o1.w = acc[i][7] + bv1.w;
    if (ACT == 1) {
      o0.x = o0.x >= 0.f ? o0.x : 0.2f * o0.x;  o0.y = o0.y >= 0.f ? o0.y : 0.2f * o0.y;
      o0.z = o0.z >= 0.f ? o0.z : 0.2f * o0.z;  o0.w = o0.w >= 0.f ? o0.w : 0.2f * o0.w;
      o1.x = o1.x >= 0.f ? o1.x : 0.2f * o1.x;  o1.y = o1.y >= 0.f ? o1.y : 0.2f * o1.y;
      o1.z = o1.z >= 0.f ? o1.z : 0.2f * o1.z;  o1.w = o1.w >= 0.f ? o1.w : 0.2f * o1.w;
    }
    *(float4*)(C + (size_t)m * N + bn + tx * 8)     = o0;
    *(float4*)(C + (size_t)m * N + bn + tx * 8 + 4) = o1;
  }
}

// ---------- LSTM step (unchanged from R4) ----------
__global__ __launch_bounds__(256) void lstm_step_kernel(
    const __half* __restrict__ xzf, const __half* __restrict__ xzb,
    const float* __restrict__ Uf, const float* __restrict__ Ub,
    const int* __restrict__ text,
    const __half* __restrict__ hprev, __half* __restrict__ hnext,
    float* __restrict__ cbuf, int s,
    __half* __restrict__ hs_out, float* __restrict__ hT_out) {
  __shared__ __align__(16) float s_zp[32 * 288];
  __shared__ __align__(16) float s_z[32 * 32];
  __half* s_h = (__half*)s_zp;

  const int t   = threadIdx.x;
  const int bi  = blockIdx.x;
  const int dir = bi >> 7;
  const int rh  = (bi >> 6) & 1;
  const int cb  = bi & 63;
  const int b0  = rh * 32;
  const int hc0 = cb * 8;
  const int tt  = dir ? (NS - 1 - s) : s;
  const __half* xz = dir ? xzb : xzf;
  const float* U = dir ? Ub : Uf;
  const int hbase = dir * NH;

  const int cg = t & 7;
  const int q  = cg & 3;
  const int jp = cg >> 2;
  const int ks = (t >> 3) & 7;
  const int rw = t >> 6;

  if (s > 0) {
#pragma unroll
    for (int i = 0; i < 8; i++) {
      int e   = i * 256 + t;
      int row = e >> 6;
      int ch  = e & 63;
      int pc  = ch ^ ((ch >> 3) & 7);
      *(uint4*)(s_h + row * 512 + pc * 8) =
          *(const uint4*)(hprev + (size_t)(b0 + row) * 1024 + hbase + ch * 8);
    }
    __syncthreads();
    float4 pacc[8];
#pragma unroll
    for (int r = 0; r < 8; r++) pacc[r] = make_float4(0.f, 0.f, 0.f, 0.f);
    const int ucol = q * NH + hc0 + jp * 4;
    int hoff[8];
#pragma unroll
    for (int kt = 0; kt < 8; kt++) hoff[kt] = (ks * 8 + (kt ^ ks)) * 8;
#pragma unroll
    for (int kt = 0; kt < 8; kt++) {
      float4 u[8];
#pragma unroll
      for (int kk = 0; kk < 8; kk++)
        u[kk] = *(const float4*)(U + (size_t)(ks * 64 + kt * 8 + kk) * N4H + ucol);
#pragma unroll
      for (int r = 0; r < 8; r++) {
        uint4 hraw = *(const uint4*)(s_h + (rw * 8 + r) * 512 + hoff[kt]);
        const __half2* hp2 = (const __half2*)&hraw;
        float hv[8];
#pragma unroll
        for (int p = 0; p < 4; p++) {
          float2 f = __half22float2(hp2[p]);
          hv[2 * p] = f.x; hv[2 * p + 1] = f.y;
        }
#pragma unroll
        for (int kk = 0; kk < 8; kk++) {
          pacc[r].x += hv[kk] * u[kk].x;
          pacc[r].y += hv[kk] * u[kk].y;
          pacc[r].z += hv[kk] * u[kk].z;
          pacc[r].w += hv[kk] * u[kk].w;
        }
      }
    }
    __syncthreads();
#pragma unroll
    for (int r = 0; r < 8; r++) {
      float* zp = &s_zp[(rw * 8 + r) * 288 + (q * 8 + jp * 4) * 9 + ks];
      zp[0] = pacc[r].x; zp[9] = pacc[r].y; zp[18] = pacc[r].z; zp[27] = pacc[r].w;
    }
  }
  __syncthreads();

#pragma unroll
  for (int dd = 0; dd < 4; dd++) {
    int v = dd * 256 + t;
    int r = v >> 5, zc = v & 31;
    float sum = 0.f;
    if (s > 0) {
      const float* zp = &s_zp[r * 288 + zc * 9];
#pragma unroll
      for (int k = 0; k < 8; k++) sum += zp[k];
    }
    int gcol = (zc >> 3) * NH + hc0 + (zc & 7);
    sum += __half2float(xz[((size_t)(b0 + r) * NS + tt) * N4H + gcol]);
    s_z[r * 32 + zc] = sum;
  }
  __syncthreads();

  {
    int r = t >> 3, j = t & 7;
    float zi = s_z[r * 32 + j];
    float zf = s_z[r * 32 + 8 + j];
    float zg = s_z[r * 32 + 16 + j];
    float zo = s_z[r * 32 + 24 + j];
    size_t cidx = (size_t)(b0 + r) * 1024 + hbase + hc0 + j;
    float cprev = (s > 0) ? cbuf[cidx] : 0.f;
    float hold  = (s > 0) ? __half2float(hprev[cidx]) : 0.f;
    float ig = 1.f / (1.f + expf(-zi));
    float fg = 1.f / (1.f + expf(-zf));
    float gv = tanhf(zg);
    float og = 1.f / (1.f + expf(-zo));
    float cn = fg * cprev + ig * gv;
    float hn = og * tanhf(cn);
    bool m = text[(b0 + r) * NS + tt] != 0;
    float c = m ? cn : cprev;
    float h = m ? hn : hold;
    cbuf[cidx] = c;
    hnext[cidx] = __float2half(h);
    if (hs_out) hs_out[((size_t)(b0 + r) * NS + tt) * 1024 + hbase + hc0 + j] = __float2half(h);
    if (hT_out && s == NS - 1) hT_out[cidx] = h;
  }
}

__global__ void final_kernel(const float* __restrict__ a1, const float* __restrict__ w,
                             const float* __restrict__ bias, float* __restrict__ out) {
  const int b = blockIdx.x, t = threadIdx.x;
  float v = a1[b * 256 + t] * w[t];
#pragma unroll
  for (int off = 32; off > 0; off >>= 1) v += __shfl_down(v, off, 64);
  __shared__ float red[4];
  if ((t & 63) == 0) red[t >> 6] = v;
  __syncthreads();
  if (t == 0) out[b] = (red[0] + red[1]) + (red[2] + red[3]) + bias[0];
}

extern "C" void kernel_launch(void* const* d_in, const int* in_sizes, int n_in,
                              void* d_out, int out_size, void* d_ws, size_t ws_size,
                              hipStream_t stream) {
  const int*   text = (const int*)  d_in[0];
  const float* emb  = (const float*)d_in[1];
  const float* W0f  = (const float*)d_in[2];
  const float* U0f  = (const float*)d_in[3];
  const float* b0f  = (const float*)d_in[4];
  const float* W0b  = (const float*)d_in[5];
  const float* U0b  = (const float*)d_in[6];
  const float* b0b  = (const float*)d_in[7];
  const float* W1f  = (const float*)d_in[8];
  const float* U1f  = (const float*)d_in[9];
  const float* b1f  = (const float*)d_in[10];
  const float* W1b  = (const float*)d_in[11];
  const float* U1b  = (const float*)d_in[12];
  const float* b1b  = (const float*)d_in[13];
  const float* d0w  = (const float*)d_in[14];
  const float* d0b  = (const float*)d_in[15];
  const float* d1w  = (const float*)d_in[16];
  const float* d1b  = (const float*)d_in[17];
  const float* d2w  = (const float*)d_in[18];
  const float* d2b  = (const float*)d_in[19];
  float* out = (float*)d_out;

  // workspace carve: byte-identical to R4's proven-safe 168,955,904 B
  char* p = (char*)d_ws;
  __half* xzA = (__half*)p;  p += (size_t)NB * NS * N4H * 2;   // 67,108,864
  __half* xzB = (__half*)p;  p += (size_t)NB * NS * N4H * 2;   // 67,108,864
  char* region1 = p;         p += (size_t)NB * NS * 1024 * 2;  // 33,554,432
  _Float16* x_emb = (_Float16*)region1;   // 16384 x 320 fp16, dead before hs0
  __half*   hs0   = (__half*)region1;     // 16384 x 1024 fp16
  __half* hp0  = (__half*)p;  p += 64 * 1024 * 2;
  __half* hp1  = (__half*)p;  p += 64 * 1024 * 2;
  float*  cbuf = (float*)p;   p += 64 * 1024 * 4;
  float*  feat = (float*)p;   p += 64 * 1024 * 4;
  float*  a0   = (float*)p;   p += 64 * 512 * 4;
  float*  a1   = (float*)p;   p += 64 * 256 * 4;

  hipLaunchKernelGGL(embed_f16_kernel, dim3(4096), dim3(256), 0, stream, text, emb, x_emb);

  dim3 gmf(16, 128);
  hipLaunchKernelGGL(gemm_mfma_kernel, gmf, dim3(256), 0, stream, x_emb, W0f, b0f, xzA, 16384, N4H, NDP, ND);
  hipLaunchKernelGGL(gemm_mfma_kernel, gmf, dim3(256), 0, stream, x_emb, W0b, b0b, xzB, 16384, N4H, NDP, ND);

  for (int s = 0; s < NS; s++) {
    const __half* hp = (s & 1) ? hp1 : hp0;
    __half*       hn = (s & 1) ? hp0 : hp1;
    lstm_step_kernel<<<dim3(256), dim3(256), 0, stream>>>(
        xzA, xzB, U0f, U0b, text, hp, hn, cbuf, s, hs0, (float*)nullptr);
  }

  hipLaunchKernelGGL(gemm_mfma_kernel, gmf, dim3(256), 0, stream, (const _Float16*)hs0, W1f, b1f, xzA, 16384, N4H, 1024, 1024);
  hipLaunchKernelGGL(gemm_mfma_kernel, gmf, dim3(256), 0, stream, (const _Float16*)hs0, W1b, b1b, xzB, 16384, N4H, 1024, 1024);

  for (int s = 0; s < NS; s++) {
    const __half* hp = (s & 1) ? hp1 : hp0;
    __half*       hn = (s & 1) ? hp0 : hp1;
    lstm_step_kernel<<<dim3(256), dim3(256), 0, stream>>>(
        xzA, xzB, U1f, U1b, text, hp, hn, cbuf, s, (__half*)nullptr, feat);
  }

  gemm_kernel<1><<<dim3(4, 1), dim3(256), 0, stream>>>(feat, d0w, d0b, a0, 64, 512, 1024);
  gemm_kernel<1><<<dim3(2, 1), dim3(256), 0, stream>>>(a0, d1w, d1b, a1, 64, 256, 512);
  hipLaunchKernelGGL(final_kernel, dim3(64), dim3(256), 0, stream, a1, d2w, d2b, out);
}